// Round 8
// baseline (133.732 us; speedup 1.0000x reference)
//
#include <hip/hip_runtime.h>
#include <hip/hip_bf16.h>

#define H_DIM   64
#define T_STEPS 128
#define B_TOT   4096
#define BB      16    // rows per block (full M tile)
#define SK      72    // padded row stride in halves for sX/sH
#define NTHREADS 512  // 8 waves; wave w owns h-cols w*8..w*8+7, all 4 gates (2 gates per N-tile)
#define XBATCH  8     // x prefetch depth (steps per global-load burst)

typedef _Float16 half8  __attribute__((ext_vector_type(8)));
typedef __fp16   fp16x2 __attribute__((ext_vector_type(2)));
typedef __attribute__((ext_vector_type(4))) float f32x4;

#if __has_builtin(__builtin_amdgcn_exp2f)
#define EXP2(x) __builtin_amdgcn_exp2f(x)
#else
#define EXP2(x) exp2f(x)
#endif

// Weights/biases pre-scaled by log2(e) (i,f,o) or 2*log2(e) (g): activations
// are raw exp2-domain, no per-activation multiply.
__device__ __forceinline__ float sigmoid2(float xp) {      // xp = x*log2e
    return __builtin_amdgcn_rcpf(1.0f + EXP2(-xp));        // exact at +-inf
}
__device__ __forceinline__ float tanh2(float xp) {         // xp = 2*log2e*x
    return fmaf(-2.0f, __builtin_amdgcn_rcpf(EXP2(xp) + 1.0f), 1.0f);
}

// lane l <-> l^8 exchange within each 16-lane row: row_ror:8 DPP (VALU speed,
// replaces ds_bpermute-based __shfl_xor, ~120cy DS latency -> ~2cy).
__device__ __forceinline__ float xor8_dpp(float v) {
    return __int_as_float(__builtin_amdgcn_mov_dpp(
        __float_as_int(v), 0x128 /*row_ror:8*/, 0xf, 0xf, false));
}

// A = [x (64) | h (64)] f16, K=128, M=16 rows. Weights in registers as f16 B-frags.
// B-fragments pack TWO gates' 8-col slices per 16-wide N-tile:
//   tile0 = [ i cols w*8..+7 | f cols w*8..+7 ],  tile1 = [ g | o ]
// i<->f / g<->o exchange via DPP xor-8; one barrier per step.
__global__ __launch_bounds__(NTHREADS) void lstm_fused(
    const int* __restrict__ inst, const float* __restrict__ embed,
    const float* __restrict__ Wih, const float* __restrict__ Whh,
    const float* __restrict__ bih, const float* __restrict__ bhh,
    float* __restrict__ out)
{
    __shared__ __align__(16) _Float16 sX[2][BB][SK];   // 4.6 KB  x staging (f16)
    __shared__ __align__(16) _Float16 sH[2][BB][SK];   // 4.6 KB  h staging (f16)
    __shared__ int sInst[BB * T_STEPS];                // 8 KB

    const int tid  = (int)threadIdx.x;
    const int w    = tid >> 6;          // wave 0..7
    const int l    = tid & 63;
    const int lrow = l & 15;            // A-row (m) / packed-n for B & C/D
    const int lk   = l >> 4;            // k-block; C/D rows are lk*4 + 0..3
    const bool losd = (lrow < 8);       // low side of the packed tile
    const int c    = w * 8 + (lrow & 7);   // h-column this thread updates
    const int b0   = (int)blockIdx.x * BB;

    const float L2E = 1.4426950408889634f;

    // stage this block's instruction indices (16 rows x 128 steps, contiguous)
    for (int i = tid; i < BB * T_STEPS; i += NTHREADS)
        sInst[i] = inst[b0 * T_STEPS + i];

    // zero h buffer 0 (h0 = 0); sH[1] fully overwritten at step 0's publish
    for (int i = tid; i < BB * SK; i += NTHREADS)
        ((_Float16*)sH)[i] = (_Float16)0.0f;
    __syncthreads();

    // weight B-fragments (f16, exp2-prescaled): tile q, gate = q*2 + (lrow>>3)
    // kf 0,1 -> W_ih k 0..63 ; kf 2,3 -> W_hh k 0..63
    half8 wf[2][4];
    float bias[2];
#pragma unroll
    for (int q = 0; q < 2; ++q) {
        const int gate = q * 2 + (lrow >> 3);
        const float wscale = (gate == 2) ? 2.0f * L2E : L2E;  // g feeds tanh(2x form)
        const int gcol = gate * 64 + c;               // W output row 0..255
        bias[q] = (bih[gcol] + bhh[gcol]) * wscale;
#pragma unroll
        for (int kf = 0; kf < 4; ++kf) {
            const float* src = (kf < 2 ? Wih : Whh) + (long)gcol * H_DIM + (kf & 1) * 32 + lk * 8;
            half8 v;
#pragma unroll
            for (int j = 0; j < 8; ++j) v[j] = (_Float16)(src[j] * wscale);
            wf[q][kf] = v;
        }
    }

    // x mapping: 512 threads = 16 rows x 32 float2 chunks, exact cover
    const int xr = tid >> 5;       // 0..15
    const int xc = tid & 31;       // 0..31
    {   // x(0) straight to LDS
        const int idx = sInst[xr * T_STEPS + 0];
        const float2 xv = *reinterpret_cast<const float2*>(embed + (long)idx * H_DIM + xc * 2);
        fp16x2 hp = __builtin_amdgcn_cvt_pkrtz(xv.x, xv.y);
        *reinterpret_cast<fp16x2*>(&sX[0][xr][xc * 2]) = hp;
    }

    // register x-buffer: entry (tt-1)&7 holds x(tt); prologue loads x(1..8)
    float2 xbuf[XBATCH];
#pragma unroll
    for (int j = 0; j < XBATCH; ++j) {
        const int idx = sInst[xr * T_STEPS + 1 + j];
        xbuf[j] = *reinterpret_cast<const float2*>(embed + (long)idx * H_DIM + xc * 2);
    }
    __syncthreads();

    // this thread updates rows lk*4 + (losd?0:2) + j, j=0..1, column c
    float creg[2] = {0.f, 0.f};
    float hreg[2] = {0.f, 0.f};

    for (int t = 0; t < T_STEPS; ++t) {
        const int buf = t & 1;
        const int ob  = buf ^ 1;
        const bool pf = (t + 1 < T_STEPS);

        // x for step t+1, loaded >=1 step (usually 8) ago
        const float2 xcur = xbuf[t & (XBATCH - 1)];

        // refill burst once per XBATCH steps: x(t+2 .. t+9) -> entries 0..7
        // (issued early; ~1 full step of compute hides the L2/L3 latency)
        if ((t & (XBATCH - 1)) == (XBATCH - 1) && pf) {
#pragma unroll
            for (int j = 0; j < XBATCH; ++j) {
                const int tt = t + 2 + j;
                if (tt < T_STEPS) {
                    const int idx = sInst[xr * T_STEPS + tt];
                    xbuf[j] = *reinterpret_cast<const float2*>(embed + (long)idx * H_DIM + xc * 2);
                }
            }
        }

        // A-fragments (f16): lane (m=lrow, lk) reads 16B contiguous
        half8 a0 = *reinterpret_cast<const half8*>(&sX[buf][lrow][lk * 8]);
        half8 a1 = *reinterpret_cast<const half8*>(&sX[buf][lrow][32 + lk * 8]);
        half8 a2 = *reinterpret_cast<const half8*>(&sH[buf][lrow][lk * 8]);
        half8 a3 = *reinterpret_cast<const half8*>(&sH[buf][lrow][32 + lk * 8]);

        // 2 packed gate tiles; each split into two 2-deep MFMA chains for ILP
        f32x4 acc[2];
#pragma unroll
        for (int q = 0; q < 2; ++q) {
            f32x4 pA = {bias[q], bias[q], bias[q], bias[q]};
            f32x4 pB = {0.f, 0.f, 0.f, 0.f};
            pA = __builtin_amdgcn_mfma_f32_16x16x32_f16(a0, wf[q][0], pA, 0, 0, 0);
            pB = __builtin_amdgcn_mfma_f32_16x16x32_f16(a1, wf[q][1], pB, 0, 0, 0);
            pA = __builtin_amdgcn_mfma_f32_16x16x32_f16(a2, wf[q][2], pA, 0, 0, 0);
            pB = __builtin_amdgcn_mfma_f32_16x16x32_f16(a3, wf[q][3], pB, 0, 0, 0);
            acc[q] = pA + pB;
        }

        // intra-wave gate exchange across the packed halves (lane ^ 8, DPP)
        const float e0 = xor8_dpp(losd ? acc[0][2] : acc[0][0]);  // vf(r0) / vi(r2)
        const float e1 = xor8_dpp(losd ? acc[0][3] : acc[0][1]);  // vf(r1) / vi(r3)
        const float e2 = xor8_dpp(losd ? acc[1][2] : acc[1][0]);  // vo(r0) / vg(r2)
        const float e3 = xor8_dpp(losd ? acc[1][3] : acc[1][1]);  // vo(r1) / vg(r3)

        // cell update for this thread's 2 rows (gate order i,f,g,o), exp2 domain
#pragma unroll
        for (int j = 0; j < 2; ++j) {
            const int r  = (losd ? 0 : 2) + j;
            const float ea = j ? e1 : e0;
            const float eb = j ? e3 : e2;
            const float vi = losd ? acc[0][r] : ea;
            const float vf = losd ? ea        : acc[0][r];
            const float vg = losd ? acc[1][r] : eb;
            const float vo = losd ? eb        : acc[1][r];
            const float iv = sigmoid2(vi);
            const float fv = sigmoid2(vf);
            const float gv = tanh2(vg);
            const float ov = sigmoid2(vo);
            const float cn = fv * creg[j] + iv * gv;
            creg[j] = cn;
            hreg[j] = ov * tanh2(cn * (2.0f * L2E));

            // publish h (f16, RNE) for next step
            if (pf) {
                const int row = lk * 4 + r;
                sH[ob][row][c] = (_Float16)hreg[j];
            }
        }

        // publish prefetched x (f16, pkrtz) into next buffer
        if (pf) {
            fp16x2 hp = __builtin_amdgcn_cvt_pkrtz(xcur.x, xcur.y);
            *reinterpret_cast<fp16x2*>(&sX[ob][xr][xc * 2]) = hp;
        }
        __syncthreads();   // sX/sH[ob] visible before next step
    }

    // final h (f32) -> out[B][H]; each thread owns 2 (row, col=c) elements
#pragma unroll
    for (int j = 0; j < 2; ++j) {
        const int row = lk * 4 + (losd ? 0 : 2) + j;
        out[(long)(b0 + row) * H_DIM + c] = hreg[j];
    }
}

extern "C" void kernel_launch(void* const* d_in, const int* in_sizes, int n_in,
                              void* d_out, int out_size, void* d_ws, size_t ws_size,
                              hipStream_t stream) {
    const int*   inst  = (const int*)  d_in[0];
    const float* embed = (const float*)d_in[1];
    const float* Wih   = (const float*)d_in[2];
    const float* Whh   = (const float*)d_in[3];
    const float* bih   = (const float*)d_in[4];
    const float* bhh   = (const float*)d_in[5];
    float* out = (float*)d_out;

    lstm_fused<<<B_TOT / BB, NTHREADS, 0, stream>>>(inst, embed, Wih, Whh, bih, bhh, out);
}

// Round 9
// 93.371 us; speedup vs baseline: 1.4323x; 1.4323x over previous
//
#include <hip/hip_runtime.h>
#include <hip/hip_bf16.h>

#define H_DIM   64
#define T_STEPS 128
#define B_TOT   4096
#define BB      16    // rows per block (full M tile)
#define SK      72    // padded row stride in halves for sX/sH
#define NTHREADS 512  // 8 waves; wave w owns h-cols w*8..w*8+7, all 4 gates (2 gates per N-tile)
#define XBATCH  8     // x prefetch depth (steps per global-load burst); MUST divide T_STEPS

typedef _Float16 half8  __attribute__((ext_vector_type(8)));
typedef __fp16   fp16x2 __attribute__((ext_vector_type(2)));
typedef __attribute__((ext_vector_type(4))) float f32x4;

#if __has_builtin(__builtin_amdgcn_exp2f)
#define EXP2(x) __builtin_amdgcn_exp2f(x)
#else
#define EXP2(x) exp2f(x)
#endif

// Weights/biases pre-scaled by log2(e) (i,f,o) or 2*log2(e) (g): activations
// are raw exp2-domain, no per-activation multiply.
__device__ __forceinline__ float sigmoid2(float xp) {      // xp = x*log2e
    return __builtin_amdgcn_rcpf(1.0f + EXP2(-xp));        // exact at +-inf
}
__device__ __forceinline__ float tanh2(float xp) {         // xp = 2*log2e*x
    return fmaf(-2.0f, __builtin_amdgcn_rcpf(EXP2(xp) + 1.0f), 1.0f);
}

// lane l <-> l^8 exchange within each 16-lane row: row_ror:8 DPP (VALU speed).
__device__ __forceinline__ float xor8_dpp(float v) {
    return __int_as_float(__builtin_amdgcn_mov_dpp(
        __float_as_int(v), 0x128 /*row_ror:8*/, 0xf, 0xf, false));
}

// A = [x (64) | h (64)] f16, K=128, M=16 rows. Weights in registers as f16 B-frags.
// B-fragments pack TWO gates' 8-col slices per 16-wide N-tile:
//   tile0 = [ i cols w*8..+7 | f cols w*8..+7 ],  tile1 = [ g | o ]
// i<->f / g<->o exchange via DPP xor-8; one barrier per step.
// Time loop is unrolled in XBATCH chunks so the x register-buffer is only ever
// indexed by compile-time constants (rule #20: runtime-indexed reg arrays spill).
__global__ __launch_bounds__(NTHREADS) void lstm_fused(
    const int* __restrict__ inst, const float* __restrict__ embed,
    const float* __restrict__ Wih, const float* __restrict__ Whh,
    const float* __restrict__ bih, const float* __restrict__ bhh,
    float* __restrict__ out)
{
    __shared__ __align__(16) _Float16 sX[2][BB][SK];   // 4.6 KB  x staging (f16)
    __shared__ __align__(16) _Float16 sH[2][BB][SK];   // 4.6 KB  h staging (f16)
    __shared__ int sInst[BB * T_STEPS];                // 8 KB

    const int tid  = (int)threadIdx.x;
    const int w    = tid >> 6;          // wave 0..7
    const int l    = tid & 63;
    const int lrow = l & 15;            // A-row (m) / packed-n for B & C/D
    const int lk   = l >> 4;            // k-block; C/D rows are lk*4 + 0..3
    const bool losd = (lrow < 8);       // low side of the packed tile
    const int c    = w * 8 + (lrow & 7);   // h-column this thread updates
    const int b0   = (int)blockIdx.x * BB;

    const float L2E = 1.4426950408889634f;

    // stage this block's instruction indices (16 rows x 128 steps, contiguous)
    for (int i = tid; i < BB * T_STEPS; i += NTHREADS)
        sInst[i] = inst[b0 * T_STEPS + i];

    // zero h buffer 0 (h0 = 0); sH[1] fully overwritten at step 0's publish
    for (int i = tid; i < BB * SK; i += NTHREADS)
        ((_Float16*)sH)[i] = (_Float16)0.0f;
    __syncthreads();

    // weight B-fragments (f16, exp2-prescaled): tile q, gate = q*2 + (lrow>>3)
    // kf 0,1 -> W_ih k 0..63 ; kf 2,3 -> W_hh k 0..63
    half8 wf[2][4];
    float bias[2];
#pragma unroll
    for (int q = 0; q < 2; ++q) {
        const int gate = q * 2 + (lrow >> 3);
        const float wscale = (gate == 2) ? 2.0f * L2E : L2E;  // g feeds tanh(2x form)
        const int gcol = gate * 64 + c;               // W output row 0..255
        bias[q] = (bih[gcol] + bhh[gcol]) * wscale;
#pragma unroll
        for (int kf = 0; kf < 4; ++kf) {
            const float* src = (kf < 2 ? Wih : Whh) + (long)gcol * H_DIM + (kf & 1) * 32 + lk * 8;
            half8 v;
#pragma unroll
            for (int j = 0; j < 8; ++j) v[j] = (_Float16)(src[j] * wscale);
            wf[q][kf] = v;
        }
    }

    // x mapping: 512 threads = 16 rows x 32 float2 chunks, exact cover
    const int xr = tid >> 5;       // 0..15
    const int xc = tid & 31;       // 0..31
    {   // x(0) straight to LDS
        const int idx = sInst[xr * T_STEPS + 0];
        const float2 xv = *reinterpret_cast<const float2*>(embed + (long)idx * H_DIM + xc * 2);
        fp16x2 hp = __builtin_amdgcn_cvt_pkrtz(xv.x, xv.y);
        *reinterpret_cast<fp16x2*>(&sX[0][xr][xc * 2]) = hp;
    }

    // register x-buffer: entry (tt-1)&7 holds x(tt); prologue loads x(1..8).
    // Only static indices below (unrolled loops) -> stays in VGPRs.
    float2 xbuf[XBATCH];
#pragma unroll
    for (int j = 0; j < XBATCH; ++j) {
        const int idx = sInst[xr * T_STEPS + 1 + j];
        xbuf[j] = *reinterpret_cast<const float2*>(embed + (long)idx * H_DIM + xc * 2);
    }
    __syncthreads();

    // this thread updates rows lk*4 + (losd?0:2) + j, j=0..1, column c
    float creg[2] = {0.f, 0.f};
    float hreg[2] = {0.f, 0.f};

    for (int tb = 0; tb < T_STEPS; tb += XBATCH) {
#pragma unroll
        for (int j = 0; j < XBATCH; ++j) {
            const int t   = tb + j;
            const int buf = j & 1;          // tb is a multiple of 8 -> (t&1) == (j&1), static
            const int ob  = buf ^ 1;
            const bool pf = (t + 1 < T_STEPS);

            // x for step t+1, loaded >=1 step (usually 8) ago; static index j
            const float2 xcur = xbuf[j];

            // refill burst once per XBATCH steps: x(t+2 .. t+9) -> entries 0..7
            // (issued before the MFMAs; a full step of compute hides the latency,
            //  and only this one barrier in 8 drains a non-empty vmcnt)
            if (j == XBATCH - 1 && pf) {
#pragma unroll
                for (int jj = 0; jj < XBATCH; ++jj) {
                    const int tt = t + 2 + jj;
                    if (tt < T_STEPS) {
                        const int idx = sInst[xr * T_STEPS + tt];
                        xbuf[jj] = *reinterpret_cast<const float2*>(embed + (long)idx * H_DIM + xc * 2);
                    }
                }
            }

            // A-fragments (f16): lane (m=lrow, lk) reads 16B contiguous
            half8 a0 = *reinterpret_cast<const half8*>(&sX[buf][lrow][lk * 8]);
            half8 a1 = *reinterpret_cast<const half8*>(&sX[buf][lrow][32 + lk * 8]);
            half8 a2 = *reinterpret_cast<const half8*>(&sH[buf][lrow][lk * 8]);
            half8 a3 = *reinterpret_cast<const half8*>(&sH[buf][lrow][32 + lk * 8]);

            // 2 packed gate tiles; each split into two 2-deep MFMA chains for ILP
            f32x4 acc[2];
#pragma unroll
            for (int q = 0; q < 2; ++q) {
                f32x4 pA = {bias[q], bias[q], bias[q], bias[q]};
                f32x4 pB = {0.f, 0.f, 0.f, 0.f};
                pA = __builtin_amdgcn_mfma_f32_16x16x32_f16(a0, wf[q][0], pA, 0, 0, 0);
                pB = __builtin_amdgcn_mfma_f32_16x16x32_f16(a1, wf[q][1], pB, 0, 0, 0);
                pA = __builtin_amdgcn_mfma_f32_16x16x32_f16(a2, wf[q][2], pA, 0, 0, 0);
                pB = __builtin_amdgcn_mfma_f32_16x16x32_f16(a3, wf[q][3], pB, 0, 0, 0);
                acc[q] = pA + pB;
            }

            // intra-wave gate exchange across the packed halves (lane ^ 8, DPP)
            const float e0 = xor8_dpp(losd ? acc[0][2] : acc[0][0]);  // vf(r0) / vi(r2)
            const float e1 = xor8_dpp(losd ? acc[0][3] : acc[0][1]);  // vf(r1) / vi(r3)
            const float e2 = xor8_dpp(losd ? acc[1][2] : acc[1][0]);  // vo(r0) / vg(r2)
            const float e3 = xor8_dpp(losd ? acc[1][3] : acc[1][1]);  // vo(r1) / vg(r3)

            // cell update for this thread's 2 rows (gate order i,f,g,o), exp2 domain
#pragma unroll
            for (int jr = 0; jr < 2; ++jr) {
                const int r  = (losd ? 0 : 2) + jr;
                const float ea = jr ? e1 : e0;
                const float eb = jr ? e3 : e2;
                const float vi = losd ? acc[0][r] : ea;
                const float vf = losd ? ea        : acc[0][r];
                const float vg = losd ? acc[1][r] : eb;
                const float vo = losd ? eb        : acc[1][r];
                const float iv = sigmoid2(vi);
                const float fv = sigmoid2(vf);
                const float gv = tanh2(vg);
                const float ov = sigmoid2(vo);
                const float cn = fv * creg[jr] + iv * gv;
                creg[jr] = cn;
                hreg[jr] = ov * tanh2(cn * (2.0f * L2E));

                // publish h (f16, RNE) for next step
                if (pf) {
                    const int row = lk * 4 + r;
                    sH[ob][row][c] = (_Float16)hreg[jr];
                }
            }

            // publish prefetched x (f16, pkrtz) into next buffer
            if (pf) {
                fp16x2 hp = __builtin_amdgcn_cvt_pkrtz(xcur.x, xcur.y);
                *reinterpret_cast<fp16x2*>(&sX[ob][xr][xc * 2]) = hp;
            }
            __syncthreads();   // sX/sH[ob] visible before next step
        }
    }

    // final h (f32) -> out[B][H]; each thread owns 2 (row, col=c) elements
#pragma unroll
    for (int j = 0; j < 2; ++j) {
        const int row = lk * 4 + (losd ? 0 : 2) + j;
        out[(long)(b0 + row) * H_DIM + c] = hreg[j];
    }
}

extern "C" void kernel_launch(void* const* d_in, const int* in_sizes, int n_in,
                              void* d_out, int out_size, void* d_ws, size_t ws_size,
                              hipStream_t stream) {
    const int*   inst  = (const int*)  d_in[0];
    const float* embed = (const float*)d_in[1];
    const float* Wih   = (const float*)d_in[2];
    const float* Whh   = (const float*)d_in[3];
    const float* bih   = (const float*)d_in[4];
    const float* bhh   = (const float*)d_in[5];
    float* out = (float*)d_out;

    lstm_fused<<<B_TOT / BB, NTHREADS, 0, stream>>>(inst, embed, Wih, Whh, bih, bhh, out);
}